// Round 25
// baseline (245.209 us; speedup 1.0000x reference)
//
#include <hip/hip_runtime.h>

typedef unsigned int u32;
typedef unsigned short u16;
typedef __attribute__((ext_vector_type(8))) short short8;
typedef __attribute__((ext_vector_type(4))) float f32x4;

__device__ __forceinline__ float b2f(u16 h){ u32 x = ((u32)h) << 16; return __builtin_bit_cast(float, x); }
__device__ __forceinline__ u16 f2b(float f){
  u32 x = __builtin_bit_cast(u32, f);
  x += 0x7fffu + ((x >> 16) & 1u);
  return (u16)(x >> 16);
}
#define LOH(u) ((u16)((u) & 0xffffu))
#define HIH(u) ((u16)((u) >> 16))

// fast transcendentals: v_exp_f32 computes 2^x; ~1e-6 rel err, invisible in bf16
__device__ __forceinline__ float fexp(float x){           // e^x
  return __builtin_amdgcn_exp2f(x * 1.4426950408889634f);
}
__device__ __forceinline__ float ftanh(float x){          // tanh, inf-safe
  const float e = __builtin_amdgcn_exp2f(x * 2.8853900817779268f);  // e^{2x}
  return 1.0f - 2.0f * __builtin_amdgcn_rcpf(e + 1.0f);
}
__device__ __forceinline__ float fsilu(float x){          // x*sigmoid(x)
  return x * __builtin_amdgcn_rcpf(1.0f + fexp(-x));
}

__device__ __forceinline__ void gload16(const u16* g, u16* lds){
  __builtin_amdgcn_global_load_lds((const __attribute__((address_space(1))) u32*)g,
                                   (__attribute__((address_space(3))) u32*)lds, 16, 0, 0);
}

// ---------------------------------------------------------------------------
// 128x128-block 4-wave GEMM (R11/R14/R19-proven):  C = A[M,K]*B[N,K]^T, K=1024.
// BK=32, 2-buffer 32KB LDS -> 4 blocks/CU (VGPR 56; R20: 5 blocks/CU spills).
// STAGE(next) -> vmcnt(4) -> s_barrier -> reads/MFMA -> s_barrier.
// 0-conflict XOR swizzle, setprio.  Linear x-major layout (fetch-ideal, R15).
// MODE 0: z<4 -> bf16 out via gp.C[z] (z==3 SiLU); z==4 -> Hb = tanh(XW@TW1T^T)
//         (N=128, only blockIdx.y==0 active, ldc=128).
// ---------------------------------------------------------------------------
struct G4P { const u16* A[5]; const u16* B[5]; u16* C[5]; };

template<int MODE>
__global__ __launch_bounds__(256, 4) void gemm128_k(G4P gp, float* __restrict__ Cf)
{
  __shared__ u16 lds[16384];     // 2 bufs x (A 4096 | B 4096) u16 = 32 KB
  const int tid = threadIdx.x;
  const int z = blockIdx.z;
  if (MODE == 0 && z == 4 && blockIdx.y != 0) return;   // Hb: N=128 only
  const u16* __restrict__ A  = gp.A[z];
  const u16* __restrict__ Bw = gp.B[z];
  const int wid = tid >> 6, lane = tid & 63;
  const int wr = wid >> 1, wc = wid & 1;
  const int l16 = lane & 15, kq = lane >> 4;
  const int swr = (l16 >> 1) & 3;       // read-side swizzle key
  const long row0 = (long)blockIdx.x * 128;
  const long col0 = (long)blockIdx.y * 128;

  f32x4 acc[4][4];
#pragma unroll
  for (int i = 0; i < 4; i++)
#pragma unroll
    for (int j = 0; j < 4; j++) acc[i][j] = (f32x4)0.0f;

  const int srow = tid >> 2;            // 0..63
  const int sk8 = ((tid & 3) ^ ((tid >> 3) & 3)) * 8;
  const u16* Agp = A  + (row0 + srow) * 1024 + sk8;
  const u16* Bgp = Bw + (col0 + srow) * 1024 + sk8;

  auto STAGE = [&](int buf, int kt){
    u16* Ab = lds + buf * 8192;
    u16* Bb = Ab + 4096;
    const int ko = kt * 32;
    gload16(Agp + ko,         Ab + tid * 8);
    gload16(Agp + 65536 + ko, Ab + (tid + 256) * 8);   // +64 rows
    gload16(Bgp + ko,         Bb + tid * 8);
    gload16(Bgp + 65536 + ko, Bb + (tid + 256) * 8);
  };

  STAGE(0, 0);
  const int NT = 32;   // K=1024 / BK=32
  for (int t = 0; t < NT; t++){
    const int cur = t & 1;
    if (t + 1 < NT){
      STAGE(cur ^ 1, t + 1);             // buf cur^1: reads ended at prev end-of-iter barrier
      asm volatile("s_waitcnt vmcnt(4)" ::: "memory");   // own tile-t loads landed
    } else {
      asm volatile("s_waitcnt vmcnt(0)" ::: "memory");
    }
    __builtin_amdgcn_sched_barrier(0);
    __builtin_amdgcn_s_barrier();        // promotes per-wave vmcnt to block-wide guarantee
    __builtin_amdgcn_sched_barrier(0);
    const u16* Ab = lds + cur * 8192;
    const u16* Bb = Ab + 4096;
    short8 afr[4], bfr[4];
#pragma unroll
    for (int ni = 0; ni < 4; ni++)
      bfr[ni] = *(const short8*)&Bb[(wc*64 + ni*16 + l16)*32 + (kq ^ swr)*8];
#pragma unroll
    for (int mi = 0; mi < 4; mi++)
      afr[mi] = *(const short8*)&Ab[(wr*64 + mi*16 + l16)*32 + (kq ^ swr)*8];
    __builtin_amdgcn_s_setprio(1);
#pragma unroll
    for (int mi = 0; mi < 4; mi++)
#pragma unroll
      for (int ni = 0; ni < 4; ni++)
        acc[mi][ni] = __builtin_amdgcn_mfma_f32_16x16x32_bf16(afr[mi], bfr[ni], acc[mi][ni], 0, 0, 0);
    __builtin_amdgcn_s_setprio(0);
    __builtin_amdgcn_s_barrier();        // all waves done reading buf cur
  }

  const bool SILU = (MODE == 0) && (z == 3);
  const bool TANH = (MODE == 0) && (z == 4);
  const int  ldc  = (MODE == 0 && z == 4) ? 128 : 1024;
#pragma unroll
  for (int mi = 0; mi < 4; mi++){
#pragma unroll
    for (int qq = 0; qq < 4; qq++){
      const long r = row0 + wr*64 + mi*16 + kq*4 + qq;
      if (MODE == 0){
        u16* crow = gp.C[z] + r * ldc + col0 + wc*64 + l16;
#pragma unroll
        for (int ni = 0; ni < 4; ni++){
          float v = acc[mi][ni][qq];
          if (SILU) v = fsilu(v);
          if (TANH) v = ftanh(v);
          crow[ni * 16] = f2b(v);
        }
      } else {
        float* crow = Cf + r * 1024 + col0 + wc*64 + l16;
#pragma unroll
        for (int ni = 0; ni < 4; ni++)
          crow[ni * 16] = acc[mi][ni][qq];
      }
    }
  }
}

// ---------------------------------------------------------------------------
// MIXB GEMM, full-GPU variant: C = tanh(A[8192,1024] * B[256,1024]^T), bf16.
// 64x128 tile -> grid (128,2) = 256 blocks.  4 waves 2x2, acc[2][4].
// ---------------------------------------------------------------------------
__global__ __launch_bounds__(256) void gemm_tanh64(
    const u16* __restrict__ A, const u16* __restrict__ B, u16* __restrict__ C)
{
  __shared__ u16 As[64 * 32];    // 4 KB
  __shared__ u16 Bs[128 * 32];   // 8 KB
  const int tid = threadIdx.x;
  const int wave = tid >> 6, lane = tid & 63;
  const int wr = wave >> 1, wc = wave & 1;
  const int l16 = lane & 15, kq = lane >> 4;
  const long row0 = (long)blockIdx.x * 64;
  const long col0 = (long)blockIdx.y * 128;

  f32x4 acc[2][4];
#pragma unroll
  for (int i = 0; i < 2; i++)
#pragma unroll
    for (int j = 0; j < 4; j++) acc[i][j] = (f32x4)0.0f;

  const u16* Ag  = A + (row0 + (tid >> 2)) * 1024 + (tid & 3) * 8;
  u16* Al = &As[tid * 8];
  const int c1 = tid + 256;
  const u16* Bg0 = B + (col0 + (tid >> 2)) * 1024 + (tid & 3) * 8;
  const u16* Bg1 = B + (col0 + (c1 >> 2)) * 1024 + (c1 & 3) * 8;
  u16* Bl0 = &Bs[tid * 8]; u16* Bl1 = &Bs[c1 * 8];

  for (int kk = 0; kk < 1024; kk += 32){
    __syncthreads();
    gload16(Ag + kk, Al);
    gload16(Bg0 + kk, Bl0);
    gload16(Bg1 + kk, Bl1);
    __syncthreads();
    short8 af[2], bfr[4];
#pragma unroll
    for (int mi = 0; mi < 2; mi++) af[mi]  = *(const short8*)&As[(wr*32 + mi*16 + l16)*32 + kq*8];
#pragma unroll
    for (int ni = 0; ni < 4; ni++) bfr[ni] = *(const short8*)&Bs[(wc*64 + ni*16 + l16)*32 + kq*8];
#pragma unroll
    for (int mi = 0; mi < 2; mi++)
#pragma unroll
      for (int ni = 0; ni < 4; ni++)
        acc[mi][ni] = __builtin_amdgcn_mfma_f32_16x16x32_bf16(af[mi], bfr[ni], acc[mi][ni], 0, 0, 0);
  }

#pragma unroll
  for (int mi = 0; mi < 2; mi++){
#pragma unroll
    for (int qq = 0; qq < 4; qq++){
      const long r = row0 + wr*32 + mi*16 + kq*4 + qq;
      u16* crow = C + r * 256 + col0 + wc*64 + l16;
#pragma unroll
      for (int ni = 0; ni < 4; ni++)
        crow[ni * 16] = f2b(ftanh(acc[mi][ni][qq]));
    }
  }
}

// ---------------------------------------------------------------------------
// Wo GEMM, full-pack variant: C_f32 = Z[8192,1024] * WOb[1024,1024]^T.
// 64x128 tile -> grid (128,8) = 1024 blocks = exactly 4 blocks/CU resident
// (old 128x128 grid (64,8) = 512 blocks left every CU half-empty).
// 12 KB LDS, low VGPR -> deep co-residency (the R15/R22 lever).
// ---------------------------------------------------------------------------
__global__ __launch_bounds__(256) void gemm_wo64(
    const u16* __restrict__ A, const u16* __restrict__ B, float* __restrict__ C)
{
  __shared__ u16 As[64 * 32];    // 4 KB
  __shared__ u16 Bs[128 * 32];   // 8 KB
  const int tid = threadIdx.x;
  const int wave = tid >> 6, lane = tid & 63;
  const int wr = wave >> 1, wc = wave & 1;
  const int l16 = lane & 15, kq = lane >> 4;
  const long row0 = (long)blockIdx.x * 64;
  const long col0 = (long)blockIdx.y * 128;

  f32x4 acc[2][4];
#pragma unroll
  for (int i = 0; i < 2; i++)
#pragma unroll
    for (int j = 0; j < 4; j++) acc[i][j] = (f32x4)0.0f;

  const u16* Ag  = A + (row0 + (tid >> 2)) * 1024 + (tid & 3) * 8;
  u16* Al = &As[tid * 8];
  const int c1 = tid + 256;
  const u16* Bg0 = B + (col0 + (tid >> 2)) * 1024 + (tid & 3) * 8;
  const u16* Bg1 = B + (col0 + (c1 >> 2)) * 1024 + (c1 & 3) * 8;
  u16* Bl0 = &Bs[tid * 8]; u16* Bl1 = &Bs[c1 * 8];

  for (int kk = 0; kk < 1024; kk += 32){
    __syncthreads();
    gload16(Ag + kk, Al);
    gload16(Bg0 + kk, Bl0);
    gload16(Bg1 + kk, Bl1);
    __syncthreads();
    short8 af[2], bfr[4];
#pragma unroll
    for (int mi = 0; mi < 2; mi++) af[mi]  = *(const short8*)&As[(wr*32 + mi*16 + l16)*32 + kq*8];
#pragma unroll
    for (int ni = 0; ni < 4; ni++) bfr[ni] = *(const short8*)&Bs[(wc*64 + ni*16 + l16)*32 + kq*8];
#pragma unroll
    for (int mi = 0; mi < 2; mi++)
#pragma unroll
      for (int ni = 0; ni < 4; ni++)
        acc[mi][ni] = __builtin_amdgcn_mfma_f32_16x16x32_bf16(af[mi], bfr[ni], acc[mi][ni], 0, 0, 0);
  }

#pragma unroll
  for (int mi = 0; mi < 2; mi++){
#pragma unroll
    for (int qq = 0; qq < 4; qq++){
      const long r = row0 + wr*32 + mi*16 + kq*4 + qq;
      float* crow = C + r * 1024 + col0 + wc*64 + l16;
#pragma unroll
      for (int ni = 0; ni < 4; ni++)
        crow[ni * 16] = acc[mi][ni][qq];
    }
  }
}

// ---------------------------------------------------------------------------
// Fused 5-way token-mix GEMM, z-loop INSIDE, single barrier:
// A-tile [128][160] AND all five B-tiles staged up front (80 KB dynamic LDS),
// then 5 back-to-back MFMA+epilogue passes (no per-z barriers).
// C_f = bf16(x + xx*(tm_f + acc)).  Packed (ex|exx) u32 loads hoisted to regs.
// ---------------------------------------------------------------------------
struct Mix5P { const u32* pxx; u16* out[5]; const float* tm[5]; };

__global__ __launch_bounds__(256, 2) void gemm_mix5(
    const u16* __restrict__ Am, const u16* __restrict__ W2T, Mix5P mp)
{
  extern __shared__ u16 sh[];     // A 20480 u16 | B 5*4096 u16 = 80 KB
  u16* As = sh;                   // [128][160]
  u16* Bs = sh + 20480;           // 5 x [128][32]
  const int tid = threadIdx.x;
  const int wave = tid >> 6, lane = tid & 63;
  const int wr = wave >> 1, wc = wave & 1;
  const int l16 = lane & 15, kq = lane >> 4;
  const long row0 = (long)blockIdx.x * 128;
  const long col0 = (long)blockIdx.y * 128;

  // stage A-tile [128][160]: 20 chunks/row, 2560 chunks total.
#pragma unroll
  for (int it = 0; it < 10; it++){
    const int c = tid + it * 256;
    const int r = c / 20, c8 = c - r * 20;
    gload16(Am + (row0 + r) * 256 + c8 * 8, &As[c * 8]);
  }
  // stage all five B-tiles [128][32] each: 2 chunks/thread per z.
#pragma unroll
  for (int z = 0; z < 5; z++){
    const u16* B = W2T + z * 32768;
    u16* Bz = Bs + z * 4096;
#pragma unroll
    for (int it = 0; it < 2; it++){
      const int c = tid + it * 256;
      gload16(B + (col0 + (c >> 2)) * 32 + (c & 3) * 8, &Bz[c * 8]);
    }
  }

  // hoisted packed (ex|exx) loads: 64 positions, 1 u32 each
  u32 pxx[64];
#pragma unroll
  for (int mi = 0; mi < 4; mi++)
#pragma unroll
    for (int qq = 0; qq < 4; qq++){
      const long r = row0 + wr*64 + mi*16 + kq*4 + qq;
#pragma unroll
      for (int ni = 0; ni < 4; ni++){
        const long c = col0 + wc*64 + ni*16 + l16;
        pxx[mi*16 + qq*4 + ni] = mp.pxx[r * 1024 + c];
      }
    }

  __syncthreads();   // all staging landed (drains lds-DMA + block-wide)

  for (int z = 0; z < 5; z++){
    const u16* Bz = Bs + z * 4096;
    short8 af[4], bfr[4];
#pragma unroll
    for (int mi = 0; mi < 4; mi++) af[mi]  = *(const short8*)&As[(wr*64 + mi*16 + l16)*160 + z*32 + kq*8];
#pragma unroll
    for (int ni = 0; ni < 4; ni++) bfr[ni] = *(const short8*)&Bz[(wc*64 + ni*16 + l16)*32 + kq*8];
    f32x4 acc[4][4];
#pragma unroll
    for (int i = 0; i < 4; i++)
#pragma unroll
      for (int j = 0; j < 4; j++) acc[i][j] = (f32x4)0.0f;
#pragma unroll
    for (int mi = 0; mi < 4; mi++)
#pragma unroll
      for (int ni = 0; ni < 4; ni++)
        acc[mi][ni] = __builtin_amdgcn_mfma_f32_16x16x32_bf16(af[mi], bfr[ni], acc[mi][ni], 0, 0, 0);

    const float* tm = mp.tm[z];
    float tmv[4];
#pragma unroll
    for (int ni = 0; ni < 4; ni++) tmv[ni] = tm[col0 + wc*64 + ni*16 + l16];
    u16* C = mp.out[z];
#pragma unroll
    for (int mi = 0; mi < 4; mi++){
#pragma unroll
      for (int qq = 0; qq < 4; qq++){
        const long r = row0 + wr*64 + mi*16 + kq*4 + qq;
        u16* crow = C + r * 1024 + col0 + wc*64 + l16;
#pragma unroll
        for (int ni = 0; ni < 4; ni++){
          const u32 pk = pxx[mi*16 + qq*4 + ni];
          const float xc = b2f(LOH(pk));
          const float xx = b2f(HIH(pk));
          crow[ni * 16] = f2b(xc + xx * (tmv[ni] + acc[mi][ni][qq]));
        }
      }
    }
  }
}

// ---------------------------------------------------------------------------
// Fused prep + mkxm (one launch).  y<9: weight prep slices.
// y in [9,17): XM = bf16(x + (xp-x)*tmx); PXX = bf16(x) | bf16(xp-x)<<16.
// ---------------------------------------------------------------------------
struct PrepMkP { const float* s[5]; u16* d[5];
                 const float* mw1; const float* mw2; const float* tdw1; const float* tdw2;
                 u16* w1t; u16* w2t; u16* tw1t; u16* tw2t;
                 const float* X; const float* tmx; u16* XM; u32* PXX; };
__global__ __launch_bounds__(256) void prepmk_k(PrepMkP pp)
{
  const int y = blockIdx.y;
  if (y < 9){
    const long idx = (long)blockIdx.x * 256 + threadIdx.x;
    if (y < 5){
      const float4 v = ((const float4*)pp.s[y])[idx];
      ushort4 o; o.x = f2b(v.x); o.y = f2b(v.y); o.z = f2b(v.z); o.w = f2b(v.w);
      ((ushort4*)pp.d[y])[idx] = o;
    } else if (y == 5){
      const int k = (int)(idx & 1023);       // idx = n*1024 + k
      const int n = (int)(idx >> 10);
      pp.w1t[idx] = (n < 160) ? f2b(pp.mw1[(long)k * 160 + n]) : (u16)0;
    } else if (y == 6){
      if (idx >= 163840) return;
      const int k = (int)(idx & 31);
      const int col = (int)(idx >> 5) & 1023;
      const int f = (int)(idx >> 15);
      pp.w2t[idx] = f2b(pp.mw2[f * 32768 + k * 1024 + col]);
    } else if (y == 7){
      if (idx >= 131072) return;
      const int k = (int)(idx & 1023);
      const int n = (int)(idx >> 10);
      pp.tw1t[idx] = (n < 64) ? f2b(pp.tdw1[(long)k * 64 + n]) : (u16)0;
    } else {
      if (idx >= 65536) return;
      const int k = (int)(idx & 63);
      const int n = (int)(idx >> 6);
      pp.tw2t[idx] = f2b(pp.tdw2[(long)k * 1024 + n]);
    }
    return;
  }
  // mkxm part: 8 y-slices x 1024 x-blocks = 8192 logical blocks
  const long idx = (((long)(y - 9) * 1024 + blockIdx.x) * 256 + threadIdx.x);
  const long m = idx >> 8;
  const int c4 = (int)(idx & 255) * 4;
  const float4 x = *(const float4*)(pp.X + m * 1024 + c4);
  float4 p = make_float4(0.f, 0.f, 0.f, 0.f);
  if ((m & 2047) != 0) p = *(const float4*)(pp.X + (m - 1) * 1024 + c4);
  const float4 t = *(const float4*)(pp.tmx + c4);
  ushort4 o;
  o.x = f2b(x.x + (p.x - x.x) * t.x);
  o.y = f2b(x.y + (p.y - x.y) * t.y);
  o.z = f2b(x.z + (p.z - x.z) * t.z);
  o.w = f2b(x.w + (p.w - x.w) * t.w);
  *(ushort4*)(pp.XM + m * 1024 + c4) = o;
  uint4 px;
  px.x = (u32)f2b(x.x) | ((u32)f2b(p.x - x.x) << 16);
  px.y = (u32)f2b(x.y) | ((u32)f2b(p.y - x.y) << 16);
  px.z = (u32)f2b(x.z) | ((u32)f2b(p.z - x.z) << 16);
  px.w = (u32)f2b(x.w) | ((u32)f2b(p.w - x.w) << 16);
  *(uint4*)(pp.PXX + m * 1024 + c4) = px;
}

// ---------------------------------------------------------------------------
// WKV6 stage 1 (MFMA) + fused DEC.  Block per (b,h,chunk).
//  DEC = exp(-exp(Hb@TW2T^T + td)) computed in-kernel (K=64, one 64x64 tile),
//  then: M = r̃·k̃ᵀ (masked), Y = M·V + diag·v (bf16), A = k̃ᵀ·V (bf16 out),
//  r̃ -> Rg (direct from P0c, coalesced), Pg.  P0c: 4x segmented scan,
//  KTT packed u32 stores.  Fast exp2 transcendentals.
// ---------------------------------------------------------------------------
__global__ __launch_bounds__(256) void wkv_s1(
    u16* __restrict__ Rg, const u16* __restrict__ Kg, const u16* __restrict__ Vg,
    const u16* __restrict__ Hbg, const u16* __restrict__ TW2Tg,
    const float* __restrict__ TDg, const float* __restrict__ Ug,
    u16* __restrict__ Yg, u16* __restrict__ Ag, float* __restrict__ Pg)
{
  __shared__ u16 RT_[64 * 72];     // Hb tile -> r -> r̃  [i][k]
  __shared__ u16 KT_[64 * 72];     // TW2T tile -> k -> k̃  [s][k]
  __shared__ u16 KTT_[64 * 72];    // k̃ᵀ [k][s]
  __shared__ u16 V_[64 * 72];      // V [s][j]
  __shared__ u16 VT_[64 * 72];     // Vᵀ [j][s]
  __shared__ char UD_[64 * 68 * 4];// DEC f32 [i][68], then M u16 [i][72]
  __shared__ float us_[64];
  __shared__ float td_[64];
  __shared__ float dg4_[256];
  __shared__ float dg_[64];
  __shared__ float segp_[256];     // [seg][k] local decay products
  float* D_ = (float*)UD_;
  u16*  M_  = (u16*)UD_;

  const int tid = threadIdx.x;
  const int bh = blockIdx.x >> 5, ch = blockIdx.x & 31;
  const int b = bh >> 4, h = bh & 15, cb = h * 64;
  const long rowb = (long)b * 2048 + ch * 64;

  if (tid < 64){ us_[tid] = Ug[cb + tid]; td_[tid] = TDg[cb + tid]; }

  const int iS = tid >> 2, sg = tid & 3;
  // ---- P(-1): stage Hb[rowb..+64][0..64) -> RT_, TW2T[cb..+64][64] -> KT_
  {
    const uint4* hsrc = (const uint4*)(Hbg + (rowb + iS) * 128 + sg * 16);
    uint4* hdst = (uint4*)&RT_[iS * 72 + sg * 16];
    hdst[0] = hsrc[0]; hdst[1] = hsrc[1];
    const uint4* wsrc = (const uint4*)(TW2Tg + (cb + iS) * 64 + sg * 16);
    uint4* wdst = (uint4*)&KT_[iS * 72 + sg * 16];
    wdst[0] = wsrc[0]; wdst[1] = wsrc[1];
  }
  __syncthreads();
  // ---- DEC MFMA: acc = Hb_tile @ TW2T_tile^T (K=64); D_ = exp(-exp(acc+td))
  {
    const int wave = tid >> 6, lane = tid & 63;
    const int wr = wave >> 1, wc = wave & 1;
    const int l16 = lane & 15, kq = lane >> 4;
    f32x4 dacc[2][2];
#pragma unroll
    for (int a = 0; a < 2; a++)
#pragma unroll
      for (int c = 0; c < 2; c++) dacc[a][c] = (f32x4)0.0f;
#pragma unroll
    for (int ks = 0; ks < 2; ks++){
      short8 af[2], bf[2];
#pragma unroll
      for (int mi = 0; mi < 2; mi++) af[mi] = *(const short8*)&RT_[(wr*32 + mi*16 + l16)*72 + ks*32 + kq*8];
#pragma unroll
      for (int ni = 0; ni < 2; ni++) bf[ni] = *(const short8*)&KT_[(wc*32 + ni*16 + l16)*72 + ks*32 + kq*8];
#pragma unroll
      for (int mi = 0; mi < 2; mi++)
#pragma unroll
        for (int ni = 0; ni < 2; ni++)
          dacc[mi][ni] = __builtin_amdgcn_mfma_f32_16x16x32_bf16(af[mi], bf[ni], dacc[mi][ni], 0, 0, 0);
    }
    __syncthreads();   // all RT_/KT_ reads complete before r/k/v staging overwrites
#pragma unroll
    for (int mi = 0; mi < 2; mi++)
#pragma unroll
      for (int ni = 0; ni < 2; ni++)
#pragma unroll
        for (int qq = 0; qq < 4; qq++){
          const int ii = wr*32 + mi*16 + kq*4 + qq;
          const int jj = wc*32 + ni*16 + l16;
          D_[ii * 68 + jj] = fexp(-fexp(dacc[mi][ni][qq] + td_[jj]));
        }
  }
  // ---- P0: stage r,k,v(,vT)
  {
    const long go = (rowb + iS) * 1024 + cb + sg * 16;
    uint4 a0 = *(const uint4*)(Rg + go);
    uint4 a1 = *(const uint4*)(Rg + go + 8);
    u32* rd = (u32*)&RT_[iS * 72 + sg * 16];
    rd[0]=a0.x; rd[1]=a0.y; rd[2]=a0.z; rd[3]=a0.w;
    rd[4]=a1.x; rd[5]=a1.y; rd[6]=a1.z; rd[7]=a1.w;
    a0 = *(const uint4*)(Kg + go); a1 = *(const uint4*)(Kg + go + 8);
    u32* kd = (u32*)&KT_[iS * 72 + sg * 16];
    kd[0]=a0.x; kd[1]=a0.y; kd[2]=a0.z; kd[3]=a0.w;
    kd[4]=a1.x; kd[5]=a1.y; kd[6]=a1.z; kd[7]=a1.w;
    a0 = *(const uint4*)(Vg + go); a1 = *(const uint4*)(Vg + go + 8);
    u32* vd = (u32*)&V_[iS * 72 + sg * 16];
    vd[0]=a0.x; vd[1]=a0.y; vd[2]=a0.z; vd[3]=a0.w;
    vd[4]=a1.x; vd[5]=a1.y; vd[6]=a1.z; vd[7]=a1.w;
    const u32 vw[8] = {a0.x,a0.y,a0.z,a0.w,a1.x,a1.y,a1.z,a1.w};
#pragma unroll
    for (int e = 0; e < 8; e++){
      VT_[(sg*16 + 2*e    ) * 72 + iS] = LOH(vw[e]);
      VT_[(sg*16 + 2*e + 1) * 72 + iS] = HIH(vw[e]);
    }
  }
  __syncthreads();
  // ---- P0b: diag partials with RAW r,k
  {
    const int i = tid & 63, q = tid >> 6;
    const u32* rr = (const u32*)&RT_[i * 72 + q * 16];
    const u32* kr = (const u32*)&KT_[i * 72 + q * 16];
    const float* up = &us_[q * 16];
    float ds = 0.0f;
#pragma unroll
    for (int e = 0; e < 8; e++){
      ds += b2f(LOH(rr[e])) * up[2*e]   * b2f(LOH(kr[e]));
      ds += b2f(HIH(rr[e])) * up[2*e+1] * b2f(HIH(kr[e]));
    }
    dg4_[i * 4 + q] = ds;
  }
  __syncthreads();
  // ---- P0c (4x parallel segmented scan): prefix decay; RT->r̃ (+direct Rg),
  //      KT->k̃ (+KTT packed u32)
  {
    const int k = tid & 63, seg = tid >> 6;
    if (seg == 0) dg_[k] = dg4_[k*4] + dg4_[k*4+1] + dg4_[k*4+2] + dg4_[k*4+3];
    const int i0 = seg * 16;
    float lp = 1.0f;
#pragma unroll
    for (int i = 0; i < 16; i++) lp *= D_[(i0 + i) * 68 + k];
    segp_[seg * 64 + k] = lp;
    __syncthreads();
    float pz = 1.0f;
    for (int s = 0; s < seg; s++) pz *= segp_[s * 64 + k];
    u16* rgc = Rg + (rowb + i0) * 1024 + cb + k;   // column k, coalesced per wave
#pragma unroll
    for (int i2 = 0; i2 < 8; i2++){
      u32 pkk = 0;
#pragma unroll
      for (int h = 0; h < 2; h++){
        const int ii = i0 + i2*2 + h;
        const float d = D_[ii * 68 + k];
        const int ro = ii * 72 + k;
        const u16 rb2 = f2b(b2f(RT_[ro]) * pz);
        RT_[ro] = rb2;
        rgc[(i2*2 + h) * 1024] = rb2;
        pz *= d;
        const u16 kb = f2b(b2f(KT_[ro]) * __builtin_amdgcn_rcpf(pz));
        KT_[ro] = kb;
        pkk |= ((u32)kb) << (16*h);
      }
      *(u32*)&KTT_[k * 72 + i0 + i2*2] = pkk;
    }
    if (seg == 3) Pg[((long)bh * 32 + ch) * 64 + k] = pz;
  }
  __syncthreads();
  const int wave = tid >> 6, lane = tid & 63;
  const int wr = wave >> 1, wc = wave & 1;
  const int l16 = lane & 15, kq = lane >> 4;
  // ---- P2: M = r̃·k̃ᵀ, mask s<i, store bf16 to M_
  {
    f32x4 acc[2][2];
#pragma unroll
    for (int a = 0; a < 2; a++)
#pragma unroll
      for (int c = 0; c < 2; c++) acc[a][c] = (f32x4)0.0f;
#pragma unroll
    for (int ks = 0; ks < 2; ks++){
      short8 af[2], bf[2];
#pragma unroll
      for (int mi = 0; mi < 2; mi++) af[mi] = *(const short8*)&RT_[(wr*32 + mi*16 + l16)*72 + ks*32 + kq*8];
#pragma unroll
      for (int ni = 0; ni < 2; ni++) bf[ni] = *(const short8*)&KT_[(wc*32 + ni*16 + l16)*72 + ks*32 + kq*8];
#pragma unroll
      for (int mi = 0; mi < 2; mi++)
#pragma unroll
        for (int ni = 0; ni < 2; ni++)
          acc[mi][ni] = __builtin_amdgcn_mfma_f32_16x16x32_bf16(af[mi], bf[ni], acc[mi][ni], 0, 0, 0);
    }
    __syncthreads();    // D_ dead; M_ union becomes valid
#pragma unroll
    for (int mi = 0; mi < 2; mi++)
#pragma unroll
      for (int ni = 0; ni < 2; ni++)
#pragma unroll
        for (int qq = 0; qq < 4; qq++){
          const int ii = wr*32 + mi*16 + kq*4 + qq;
          const int ss = wc*32 + ni*16 + l16;
          M_[ii * 72 + ss] = f2b(ss < ii ? acc[mi][ni][qq] : 0.0f);
        }
  }
  __syncthreads();
  // ---- P3+P4: Y = M·V + diag·v ; A = k̃ᵀ·V (bf16 out)
  {
    f32x4 accY[2][2], accA[2][2];
#pragma unroll
    for (int a = 0; a < 2; a++)
#pragma unroll
      for (int c = 0; c < 2; c++){ accY[a][c] = (f32x4)0.0f; accA[a][c] = (f32x4)0.0f; }
#pragma unroll
    for (int ks = 0; ks < 2; ks++){
      short8 am[2], ak[2], bv[2];
#pragma unroll
      for (int mi = 0; mi < 2; mi++){
        am[mi] = *(const short8*)&M_[(wr*32 + mi*16 + l16)*72 + ks*32 + kq*8];
        ak[mi] = *(const short8*)&KTT_[(wr*32 + mi*16 + l16)*72 + ks*32 + kq*8];
      }
#pragma unroll
      for (int ni = 0; ni < 2; ni++) bv[ni] = *(const short8*)&VT_[(wc*32 + ni*16 + l16)*72 + ks*32 + kq*8];
#pragma unroll
      for (int mi = 0; mi < 2; mi++)
#pragma unroll
        for (int ni = 0; ni < 2; ni++){
          accY[mi][ni] = __builtin_amdgcn_mfma_f32_16x16x32_bf16(am[mi], bv[ni], accY[mi][ni], 0, 0, 0);
          accA[mi][ni] = __builtin_amdgcn_mfma_f32_16x16x32_bf16(ak[mi], bv[ni], accA[mi][ni], 0, 0, 0);
        }
    }
    u16* abase = Ag + ((long)bh * 32 + ch) * 4096;
#pragma unroll
    for (int mi = 0; mi < 2; mi++)
#pragma unroll
      for (int qq = 0; qq < 4; qq++){
        const int ii = wr*32 + mi*16 + kq*4 + qq;
        u16* yrow = Yg + (rowb + ii) * 1024 + cb;
        u16* arow = abase + ii * 64;
#pragma unroll
        for (int ni = 0; ni < 2; ni++){
          const int jj = wc*32 + ni*16 + l16;
          const float yv = accY[mi][ni][qq] + dg_[ii] * b2f(V_[ii * 72 + jj]);
          yrow[jj] = f2b(yv);
          arow[jj] = f2b(accA[mi][ni][qq]);
        }
      }
  }
}

// ---------------------------------------------------------------------------
// WKV6 stage 2 — inter-chunk recurrence S_{c+1} = ps_c*(S_c + A_c).
// A and S in bf16 (state kept f32 in regs).  8-deep load prefetch.
// ---------------------------------------------------------------------------
__global__ __launch_bounds__(256) void wkv_s2(
    const u16* __restrict__ Ag, const float* __restrict__ Pg, u16* __restrict__ Sg)
{
  const int tid = threadIdx.x;
  const int bh = blockIdx.x >> 2, kq = blockIdx.x & 3;
  const int kk = tid >> 4, jo = tid & 15;
  const int krow = kq * 16 + kk;
  const long base = (long)bh * 32;
  float4 S = make_float4(0.f, 0.f, 0.f, 0.f);
  for (int g = 0; g < 4; g++){
    uint2 a[8]; float ps[8];
#pragma unroll
    for (int j = 0; j < 8; j++){
      const long c = base + g * 8 + j;
      a[j]  = *(const uint2*)(Ag + c * 4096 + krow * 64 + jo * 4);
      ps[j] = Pg[c * 64 + krow];
    }
#pragma unroll
    for (int j = 0; j < 8; j++){
      const long mo = (base + g * 8 + j) * 4096 + krow * 64 + jo * 4;
      uint2 so;
      so.x = (u32)f2b(S.x) | ((u32)f2b(S.y) << 16);
      so.y = (u32)f2b(S.z) | ((u32)f2b(S.w) << 16);
      *(uint2*)(Sg + mo) = so;
      const float a0 = b2f(LOH(a[j].x)), a1 = b2f(HIH(a[j].x));
      const float a2 = b2f(LOH(a[j].y)), a3 = b2f(HIH(a[j].y));
      S.x = ps[j] * (S.x + a0); S.y = ps[j] * (S.y + a1);
      S.z = ps[j] * (S.z + a2); S.w = ps[j] * (S.w + a3);
    }
  }
}

// ---------------------------------------------------------------------------
// WKV6 stage 3 + GroupNorm fused:  y = Y + r̃·S_chunkstart (ch>0), then
// per-head GN over the 64 channels this block owns, * g, write Z (bf16).
// Cross-term via MFMA (R24): r̃ [i][k] + Sᵀ [j][k] bf16 LDS, 8 MFMAs -> yt f32.
// ---------------------------------------------------------------------------
__global__ __launch_bounds__(256) void wkv_s3g(
    const u16* __restrict__ Rtg, const u16* __restrict__ Sg,
    const u16* __restrict__ Yg, const u16* __restrict__ G,
    const float* __restrict__ lng, const float* __restrict__ lnb,
    u16* __restrict__ Z)
{
  __shared__ u16 RTs[64 * 72];      // r̃ [i][k]
  __shared__ u16 STs[64 * 72];      // Sᵀ [j][k]
  __shared__ float yt[64 * 68];     // r̃·S product f32 [i][j]
  __shared__ float red1[256], red2[256];
  const int tid = threadIdx.x;
  const int bh = blockIdx.x >> 5, ch = blockIdx.x & 31;
  const int b = bh >> 4, h = bh & 15, cb = h * 64;
  const long rowb = (long)b * 2048 + ch * 64;
  const bool CROSS = (ch != 0);

  if (CROSS){
    const int iS = tid >> 2, sg4 = tid & 3;
    // r̃ rows [i][k]
    const uint4* src = (const uint4*)(Rtg + (rowb + iS) * 1024 + cb + sg4 * 16);
    uint4* dst = (uint4*)&RTs[iS * 72 + sg4 * 16];
    dst[0] = src[0]; dst[1] = src[1];
    // Sᵀ scatter: S [k][j] bf16 -> STs[j][k]
    const u16* sb = Sg + ((long)bh * 32 + ch) * 4096 + iS * 64 + sg4 * 16;
    const uint4 s0 = *(const uint4*)sb;
    const uint4 s1 = *(const uint4*)(sb + 8);
    const u32 w[8] = {s0.x, s0.y, s0.z, s0.w, s1.x, s1.y, s1.z, s1.w};
#pragma unroll
    for (int e = 0; e < 8; e++){
      STs[(sg4*16 + 2*e    ) * 72 + iS] = LOH(w[e]);
      STs[(sg4*16 + 2*e + 1) * 72 + iS] = HIH(w[e]);
    }
  }
  __syncthreads();
  if (CROSS){
    const int wave = tid >> 6, lane = tid & 63;
    const int wr = wave >> 1, wc = wave & 1;
    const int l16 = lane & 15, kq = lane >> 4;
    f32x4 acc[2][2];
#pragma unroll
    for (int a = 0; a < 2; a++)
#pragma unroll
      for (int c = 0; c < 2; c++) acc[a][c] = (f32x4)0.0f;
#pragma unroll
    for (int ks = 0; ks < 2; ks++){
      short8 af[2], bf[2];
#pragma unroll
      for (int mi = 0; mi < 2; mi++) af[mi] = *(const short8*)&RTs[(wr*32 + mi*16 + l16)*72 + ks*32 + kq*8];
#pragma unroll
      for (int ni = 0; ni < 2; ni++) bf[ni] = *(const short8*)&STs[(wc*32 + ni*16 + l16)*72 + ks*32 + kq*8];
#pragma unroll
      for (int mi = 0; mi < 2; mi++)
#pragma unroll
        for (int ni = 0; ni < 2; ni++)
          acc[mi][ni] = __builtin_amdgcn_mfma_f32_16x16x32_bf16(af[mi], bf[ni], acc[mi][ni], 0, 0, 0);
    }
#pragma unroll
    for (int mi = 0; mi < 2; mi++)
#pragma unroll
      for (int ni = 0; ni < 2; ni++)
#pragma unroll
        for (int qq = 0; qq < 4; qq++){
          const int ii = wr*32 + mi*16 + kq*4 + qq;
          const int jj = wc*32 + ni*16 + l16;
          yt[ii * 68 + jj] = acc[mi][ni][qq];
        }
  }
  __syncthreads();

  const int i_ = tid & 63, q = tid >> 6, jb = q * 16;
  float y[16];
  {
    const u32* yp = (const u32*)(Yg + (rowb + i_) * 1024 + cb + jb);
#pragma unroll
    for (int j2 = 0; j2 < 8; j2++){
      const u32 u = yp[j2];
      y[2*j2] = b2f(LOH(u)); y[2*j2+1] = b2f(HIH(u));
    }
  }
  if (CROSS){
    const float* yr = &yt[i_ * 68 + jb];
#pragma unroll
    for (int j = 0; j < 16; j++) y[j] += yr[j];
  }
  // group-norm reduce across the 4 q-quarters of each row
  float s = 0.0f, sq = 0.0f;
#pragma unroll
  for (int j = 0; j < 16; j++){ s += y[j]; sq += y[j]*y[j]; }
  red1[q * 64 + i_] = s;
  red2[q * 64 + i_] = sq;
  __syncthreads();
  const float St = red1[i_] + red1[64 + i_] + red1[128 + i_] + red1[192 + i_];
  const float Qt = red2[i_] + red2[64 + i_] + red2[128 + i_] + red2[192 + i_];
  const float mean = St * 0.015625f;
  const float var = Qt * 0.015625f - mean * mean;
  const float rstd = rsqrtf(var + 6.4e-4f);   // eps = 1e-5 * 64
  const u32* gp = (const u32*)(G + (rowb + i_) * 1024 + cb + jb);
  const float4* lgp = (const float4*)(lng + cb + jb);
  const float4* lbp = (const float4*)(lnb + cb + jb);
  u32* zo = (u32*)(Z + (rowb + i_) * 1024 + cb + jb);
#pragma unroll
  for (int j4 = 0; j4 < 4; j4++){
    const float4 lg = lgp[j4];
    const float4 lb = lbp[j4];
    const u32 g01 = gp[2*j4], g23 = gp[2*j4+1];
    const float z0 = ((y[4*j4+0]-mean)*rstd*lg.x + lb.x) * b2f(LOH(g01));
    const float z1 = ((y[4*j4+1]-mean)*rstd*lg.y + lb.y) * b2f(HIH(g01));
    const float z2 = ((y[4*j4+2]-mean)*rstd*lg.z + lb.z) * b2f(LOH(g23));
    const float z3 = ((y[4*j4+3]-mean)*rstd*lg.w + lb.w) * b2f(HIH(g23));
    zo[2*j4]   = (u32)f2b(z0) | ((u32)f2b(z1) << 16);
    zo[2*j4+1] = (u32)f2b(z2) | ((u32)f2b(z3) << 16);
  }
}

// ---------------------------------------------------------------------------
extern "C" void kernel_launch(void* const* d_in, const int* in_sizes, int n_in,
                              void* d_out, int out_size, void* d_ws, size_t ws_size,
                              hipStream_t stream)
{
  (void)in_sizes; (void)n_in; (void)out_size; (void)ws_size;
  const float* X    = (const float*)d_in[0];
  const float* TMX  = (const float*)d_in[1];
  const float* TMW  = (const float*)d_in[2];
  const float* TMK  = (const float*)d_in[3];
  const float* TMV  = (const float*)d_in[4];
  const float* TMR  = (const float*)d_in[5];
  const float* TMG  = (const float*)d_in[6];
  const float* MW1  = (const float*)d_in[7];
  const float* MW2  = (const float*)d_in[8];
  const float* TD   = (const float*)d_in[9];
  const float* TDW1 = (const float*)d_in[10];
  const float* TDW2 = (const float*)d_in[11];
  const float* U    = (const float*)d_in[12];
  const float* WR   = (const float*)d_in[13];
  const float* WK   = (const float*)d_in[14];
  const float* WV   = (const float*)d_in[15];
  const float* WG   = (const float*)d_in[16];
  const float* WO   = (const float*)d_in[17];
  const float* LNG  = (const float*)d_in[18];
  const float* LNB  = (const float*)d_in[19];

  char* ws = (char*)d_ws;
  const size_t SLOT = 16777216ULL;     // B*T*C bf16 bytes
  u16* S1 = (u16*)(ws + 0 * SLOT);     // XM  -> Rb (-> rt~)
  u16* S2 = (u16*)(ws + 1 * SLOT);     // XW  -> Y (bf16)
  u16* S3 = (u16*)(ws + 2 * SLOT);     // XK
  u16* S4 = (u16*)(ws + 3 * SLOT);     // XV  -> Z
  u16* S5 = (u16*)(ws + 4 * SLOT);     // XR
  u16* S6 = (u16*)(ws + 5 * SLOT);     // XG
  u16* S7 = (u16*)(ws + 6 * SLOT);     // PXX lo -> Kb -> Sg (bf16)
  u16* S8 = (u16*)(ws + 7 * SLOT);     // PXX hi -> Vb
  u16* S9 = (u16*)(ws + 8 * SLOT);     // Gb
  char* p = ws + 9 * SLOT;
  auto alloc = [&](size_t bytes) -> void* {
    void* q = p; p += (bytes + 255) & ~(size_t)255; return q;
  };
  u16* MIXB = (u16*)alloc(8192ULL * 256 * 2);
  u16* Hb   = (u16*)alloc(8192ULL * 128 * 2);
  u16* W1T  = (u16*)alloc(256ULL * 1024 * 2);
  u16* W2T  = (u16*)alloc(5ULL * 1024 * 32 * 2);
  u16* TW1T = (u16*)alloc(128ULL * 1024 * 2);
  u16* TW2T = (u16*)alloc(1024ULL * 64 * 2);
  u16* WRb  = (u16*)alloc(1048576ULL * 2);
  u16* WKb  = (u16*)alloc(1048576ULL * 2);
  u16* WVb  = (u16*)alloc(1048576ULL * 2);
  u16* WGb  = (u16*)alloc(1048576ULL * 2);
  u16* WOb  = (u16*)alloc(1048576ULL * 2);
  u16* Ab   = (u16*)alloc(16777216ULL);     // [bh][c][64][64] bf16
  float* Pg = (float*)alloc(524288ULL);     // [bh][c][64] f32

  u16*   XM = S1; u16* XW = S2; u16* XK = S3; u16* XV = S4; u16* XR = S5; u16* XG = S6;
  u32*   PXX = (u32*)S7;      // spans S7+S8 (32 MB)
  u16*   Rb = S1; u16* Kb = S7; u16* Vb = S8; u16* Gb = S9;
  u16*   Y   = S2;            // bf16 (xw dead after combined gemm)
  u16*   Sg  = S7;            // bf16, 16.77 MB (kb dead after s1)
  u16*   Z   = S4;            // xv dead

  // allow 80KB dynamic LDS for gemm_mix5 (idempotent, cheap host call)
  hipFuncSetAttribute(reinterpret_cast<const void*>(gemm_mix5),
                      hipFuncAttributeMaxDynamicSharedMemorySize, 81920);

  // fused weight prep + XM/PXX — one launch (independent work items)
  PrepMkP pp;
  pp.s[0]=WR; pp.s[1]=WK; pp.s[2]=WV; pp.s[3]=WG; pp.s[4]=WO;
  pp.d[0]=WRb; pp.d[1]=WKb; pp.d[2]=WVb; pp.d[3]=WGb; pp.d[4]=WOb;
  pp.mw1 = MW1; pp.mw2 = MW2; pp.tdw1 = TDW1; pp.tdw2 = TDW2;
  pp.w1t = W1T; pp.w2t = W2T; pp.tw1t = TW1T; pp.tw2t = TW2T;
  pp.X = X; pp.tmx = TMX; pp.XM = XM; pp.PXX = PXX;
  prepmk_k<<<dim3(1024, 17), 256, 0, stream>>>(pp);

  // mix160 = tanh(XM @ maa_w1)  [8192,256(pad)] — full-GPU 64x128 tiles
  gemm_tanh64<<<dim3(128, 2), 256, 0, stream>>>(XM, W1T, MIXB);

  // x{w,k,v,r,g} = x + xx*(tm + mix_f @ maa_w2_f) — one launch, single barrier
  Mix5P mp;
  mp.pxx = PXX;
  mp.out[0]=XW; mp.out[1]=XK; mp.out[2]=XV; mp.out[3]=XR; mp.out[4]=XG;
  mp.tm[0]=TMW; mp.tm[1]=TMK; mp.tm[2]=TMV; mp.tm[3]=TMR; mp.tm[4]=TMG;
  gemm_mix5<<<dim3(64, 8), 256, 81920, stream>>>(MIXB, W2T, mp);

  // r, k, v, g (z=0..3) + Hb = tanh(xw @ td_w1) (z=4, N=128) — ONE dispatch
  G4P gp;
  gp.A[0]=XR; gp.A[1]=XK; gp.A[2]=XV; gp.A[3]=XG; gp.A[4]=XW;
  gp.B[0]=WRb; gp.B[1]=WKb; gp.B[2]=WVb; gp.B[3]=WGb; gp.B[4]=TW1T;
  gp.C[0]=Rb; gp.C[1]=Kb; gp.C[2]=Vb; gp.C[3]=Gb; gp.C[4]=Hb;
  gemm128_k<0><<<dim3(64, 8, 5), 256, 0, stream>>>(gp, nullptr);

  // WKV6 chunk-parallel scan (Y bf16); s1 fuses DEC, s3 fuses GroupNorm -> Z
  wkv_s1<<<2048, 256, 0, stream>>>(Rb, Kb, Vb, Hb, TW2T, TD, U, Y, Ab, Pg);
  wkv_s2<<<256, 256, 0, stream>>>(Ab, Pg, Sg);
  wkv_s3g<<<2048, 256, 0, stream>>>(Rb, Sg, Y, Gb, LNG, LNB, Z);

  // out = z @ Wo^T   (f32 out) — full-pack 64x128 tiles, 1024 blocks
  gemm_wo64<<<dim3(128, 8), 256, 0, stream>>>(Z, WOb, (float*)d_out);
}

// Round 26
// 237.580 us; speedup vs baseline: 1.0321x; 1.0321x over previous
//
#include <hip/hip_runtime.h>

typedef unsigned int u32;
typedef unsigned short u16;
typedef __attribute__((ext_vector_type(8))) short short8;
typedef __attribute__((ext_vector_type(4))) float f32x4;

__device__ __forceinline__ float b2f(u16 h){ u32 x = ((u32)h) << 16; return __builtin_bit_cast(float, x); }
__device__ __forceinline__ u16 f2b(float f){
  u32 x = __builtin_bit_cast(u32, f);
  x += 0x7fffu + ((x >> 16) & 1u);
  return (u16)(x >> 16);
}
#define LOH(u) ((u16)((u) & 0xffffu))
#define HIH(u) ((u16)((u) >> 16))

// fast transcendentals: v_exp_f32 computes 2^x; ~1e-6 rel err, invisible in bf16
__device__ __forceinline__ float fexp(float x){           // e^x
  return __builtin_amdgcn_exp2f(x * 1.4426950408889634f);
}
__device__ __forceinline__ float ftanh(float x){          // tanh, inf-safe
  const float e = __builtin_amdgcn_exp2f(x * 2.8853900817779268f);  // e^{2x}
  return 1.0f - 2.0f * __builtin_amdgcn_rcpf(e + 1.0f);
}
__device__ __forceinline__ float fsilu(float x){          // x*sigmoid(x)
  return x * __builtin_amdgcn_rcpf(1.0f + fexp(-x));
}

__device__ __forceinline__ void gload16(const u16* g, u16* lds){
  __builtin_amdgcn_global_load_lds((const __attribute__((address_space(1))) u32*)g,
                                   (__attribute__((address_space(3))) u32*)lds, 16, 0, 0);
}

// ---------------------------------------------------------------------------
// 128x128-block 4-wave GEMM (R11/R14/R19-proven):  C = A[M,K]*B[N,K]^T, K=1024.
// BK=32, 2-buffer 32KB LDS -> 4 blocks/CU (VGPR 56; R20 showed 5 blocks/CU
// forces VGPR<=48 -> accumulator spills to scratch, 2x slower).
// STAGE(next) -> vmcnt(4) -> s_barrier -> reads/MFMA -> s_barrier.
// 0-conflict XOR swizzle, setprio.  Linear x-major layout (fetch-ideal, R15).
// MODE 0: z<4 -> bf16 out via gp.C[z] (z==3 SiLU); z==4 -> Hb = tanh(XW@TW1T^T)
//         (N=128, only blockIdx.y==0 active, ldc=128).  MODE 1: f32 out via Cf.
// ---------------------------------------------------------------------------
struct G4P { const u16* A[5]; const u16* B[5]; u16* C[5]; };

template<int MODE>
__global__ __launch_bounds__(256, 4) void gemm128_k(G4P gp, float* __restrict__ Cf)
{
  __shared__ u16 lds[16384];     // 2 bufs x (A 4096 | B 4096) u16 = 32 KB
  const int tid = threadIdx.x;
  const int z = blockIdx.z;
  if (MODE == 0 && z == 4 && blockIdx.y != 0) return;   // Hb: N=128 only
  const u16* __restrict__ A  = gp.A[z];
  const u16* __restrict__ Bw = gp.B[z];
  const int wid = tid >> 6, lane = tid & 63;
  const int wr = wid >> 1, wc = wid & 1;
  const int l16 = lane & 15, kq = lane >> 4;
  const int swr = (l16 >> 1) & 3;       // read-side swizzle key
  const long row0 = (long)blockIdx.x * 128;
  const long col0 = (long)blockIdx.y * 128;

  f32x4 acc[4][4];
#pragma unroll
  for (int i = 0; i < 4; i++)
#pragma unroll
    for (int j = 0; j < 4; j++) acc[i][j] = (f32x4)0.0f;

  const int srow = tid >> 2;            // 0..63
  const int sk8 = ((tid & 3) ^ ((tid >> 3) & 3)) * 8;
  const u16* Agp = A  + (row0 + srow) * 1024 + sk8;
  const u16* Bgp = Bw + (col0 + srow) * 1024 + sk8;

  auto STAGE = [&](int buf, int kt){
    u16* Ab = lds + buf * 8192;
    u16* Bb = Ab + 4096;
    const int ko = kt * 32;
    gload16(Agp + ko,         Ab + tid * 8);
    gload16(Agp + 65536 + ko, Ab + (tid + 256) * 8);   // +64 rows
    gload16(Bgp + ko,         Bb + tid * 8);
    gload16(Bgp + 65536 + ko, Bb + (tid + 256) * 8);
  };

  STAGE(0, 0);
  const int NT = 32;   // K=1024 / BK=32
  for (int t = 0; t < NT; t++){
    const int cur = t & 1;
    if (t + 1 < NT){
      STAGE(cur ^ 1, t + 1);             // buf cur^1: reads ended at prev end-of-iter barrier
      asm volatile("s_waitcnt vmcnt(4)" ::: "memory");   // own tile-t loads landed
    } else {
      asm volatile("s_waitcnt vmcnt(0)" ::: "memory");
    }
    __builtin_amdgcn_sched_barrier(0);
    __builtin_amdgcn_s_barrier();        // promotes per-wave vmcnt to block-wide guarantee
    __builtin_amdgcn_sched_barrier(0);
    const u16* Ab = lds + cur * 8192;
    const u16* Bb = Ab + 4096;
    short8 afr[4], bfr[4];
#pragma unroll
    for (int ni = 0; ni < 4; ni++)
      bfr[ni] = *(const short8*)&Bb[(wc*64 + ni*16 + l16)*32 + (kq ^ swr)*8];
#pragma unroll
    for (int mi = 0; mi < 4; mi++)
      afr[mi] = *(const short8*)&Ab[(wr*64 + mi*16 + l16)*32 + (kq ^ swr)*8];
    __builtin_amdgcn_s_setprio(1);
#pragma unroll
    for (int mi = 0; mi < 4; mi++)
#pragma unroll
      for (int ni = 0; ni < 4; ni++)
        acc[mi][ni] = __builtin_amdgcn_mfma_f32_16x16x32_bf16(afr[mi], bfr[ni], acc[mi][ni], 0, 0, 0);
    __builtin_amdgcn_s_setprio(0);
    __builtin_amdgcn_s_barrier();        // all waves done reading buf cur
  }

  const bool SILU = (MODE == 0) && (z == 3);
  const bool TANH = (MODE == 0) && (z == 4);
  const int  ldc  = (MODE == 0 && z == 4) ? 128 : 1024;
#pragma unroll
  for (int mi = 0; mi < 4; mi++){
#pragma unroll
    for (int qq = 0; qq < 4; qq++){
      const long r = row0 + wr*64 + mi*16 + kq*4 + qq;
      if (MODE == 0){
        u16* crow = gp.C[z] + r * ldc + col0 + wc*64 + l16;
#pragma unroll
        for (int ni = 0; ni < 4; ni++){
          float v = acc[mi][ni][qq];
          if (SILU) v = fsilu(v);
          if (TANH) v = ftanh(v);
          crow[ni * 16] = f2b(v);
        }
      } else {
        float* crow = Cf + r * 1024 + col0 + wc*64 + l16;
#pragma unroll
        for (int ni = 0; ni < 4; ni++)
          crow[ni * 16] = acc[mi][ni][qq];
      }
    }
  }
}

// ---------------------------------------------------------------------------
// MIXB GEMM, full-GPU variant: C = tanh(A[8192,1024] * B[256,1024]^T), bf16.
// 64x128 tile -> grid (128,2) = 256 blocks.  4 waves 2x2, acc[2][4].
// ---------------------------------------------------------------------------
__global__ __launch_bounds__(256) void gemm_tanh64(
    const u16* __restrict__ A, const u16* __restrict__ B, u16* __restrict__ C)
{
  __shared__ u16 As[64 * 32];    // 4 KB
  __shared__ u16 Bs[128 * 32];   // 8 KB
  const int tid = threadIdx.x;
  const int wave = tid >> 6, lane = tid & 63;
  const int wr = wave >> 1, wc = wave & 1;
  const int l16 = lane & 15, kq = lane >> 4;
  const long row0 = (long)blockIdx.x * 64;
  const long col0 = (long)blockIdx.y * 128;

  f32x4 acc[2][4];
#pragma unroll
  for (int i = 0; i < 2; i++)
#pragma unroll
    for (int j = 0; j < 4; j++) acc[i][j] = (f32x4)0.0f;

  const u16* Ag  = A + (row0 + (tid >> 2)) * 1024 + (tid & 3) * 8;
  u16* Al = &As[tid * 8];
  const int c1 = tid + 256;
  const u16* Bg0 = B + (col0 + (tid >> 2)) * 1024 + (tid & 3) * 8;
  const u16* Bg1 = B + (col0 + (c1 >> 2)) * 1024 + (c1 & 3) * 8;
  u16* Bl0 = &Bs[tid * 8]; u16* Bl1 = &Bs[c1 * 8];

  for (int kk = 0; kk < 1024; kk += 32){
    __syncthreads();
    gload16(Ag + kk, Al);
    gload16(Bg0 + kk, Bl0);
    gload16(Bg1 + kk, Bl1);
    __syncthreads();
    short8 af[2], bfr[4];
#pragma unroll
    for (int mi = 0; mi < 2; mi++) af[mi]  = *(const short8*)&As[(wr*32 + mi*16 + l16)*32 + kq*8];
#pragma unroll
    for (int ni = 0; ni < 4; ni++) bfr[ni] = *(const short8*)&Bs[(wc*64 + ni*16 + l16)*32 + kq*8];
#pragma unroll
    for (int mi = 0; mi < 2; mi++)
#pragma unroll
      for (int ni = 0; ni < 4; ni++)
        acc[mi][ni] = __builtin_amdgcn_mfma_f32_16x16x32_bf16(af[mi], bfr[ni], acc[mi][ni], 0, 0, 0);
  }

#pragma unroll
  for (int mi = 0; mi < 2; mi++){
#pragma unroll
    for (int qq = 0; qq < 4; qq++){
      const long r = row0 + wr*32 + mi*16 + kq*4 + qq;
      u16* crow = C + r * 256 + col0 + wc*64 + l16;
#pragma unroll
      for (int ni = 0; ni < 4; ni++)
        crow[ni * 16] = f2b(ftanh(acc[mi][ni][qq]));
    }
  }
}

// ---------------------------------------------------------------------------
// Fused 5-way token-mix GEMM, z-loop INSIDE, single barrier:
// A-tile [128][160] AND all five B-tiles staged up front (80 KB dynamic LDS),
// then 5 back-to-back MFMA+epilogue passes (no per-z barriers).
// C_f = bf16(x + xx*(tm_f + acc)).  Packed (ex|exx) u32 loads hoisted to regs.
// ---------------------------------------------------------------------------
struct Mix5P { const u32* pxx; u16* out[5]; const float* tm[5]; };

__global__ __launch_bounds__(256, 2) void gemm_mix5(
    const u16* __restrict__ Am, const u16* __restrict__ W2T, Mix5P mp)
{
  extern __shared__ u16 sh[];     // A 20480 u16 | B 5*4096 u16 = 80 KB
  u16* As = sh;                   // [128][160]
  u16* Bs = sh + 20480;           // 5 x [128][32]
  const int tid = threadIdx.x;
  const int wave = tid >> 6, lane = tid & 63;
  const int wr = wave >> 1, wc = wave & 1;
  const int l16 = lane & 15, kq = lane >> 4;
  const long row0 = (long)blockIdx.x * 128;
  const long col0 = (long)blockIdx.y * 128;

  // stage A-tile [128][160]: 20 chunks/row, 2560 chunks total.
#pragma unroll
  for (int it = 0; it < 10; it++){
    const int c = tid + it * 256;
    const int r = c / 20, c8 = c - r * 20;
    gload16(Am + (row0 + r) * 256 + c8 * 8, &As[c * 8]);
  }
  // stage all five B-tiles [128][32] each: 2 chunks/thread per z.
#pragma unroll
  for (int z = 0; z < 5; z++){
    const u16* B = W2T + z * 32768;
    u16* Bz = Bs + z * 4096;
#pragma unroll
    for (int it = 0; it < 2; it++){
      const int c = tid + it * 256;
      gload16(B + (col0 + (c >> 2)) * 32 + (c & 3) * 8, &Bz[c * 8]);
    }
  }

  // hoisted packed (ex|exx) loads: 64 positions, 1 u32 each
  u32 pxx[64];
#pragma unroll
  for (int mi = 0; mi < 4; mi++)
#pragma unroll
    for (int qq = 0; qq < 4; qq++){
      const long r = row0 + wr*64 + mi*16 + kq*4 + qq;
#pragma unroll
      for (int ni = 0; ni < 4; ni++){
        const long c = col0 + wc*64 + ni*16 + l16;
        pxx[mi*16 + qq*4 + ni] = mp.pxx[r * 1024 + c];
      }
    }

  __syncthreads();   // all staging landed (drains lds-DMA + block-wide)

  for (int z = 0; z < 5; z++){
    const u16* Bz = Bs + z * 4096;
    short8 af[4], bfr[4];
#pragma unroll
    for (int mi = 0; mi < 4; mi++) af[mi]  = *(const short8*)&As[(wr*64 + mi*16 + l16)*160 + z*32 + kq*8];
#pragma unroll
    for (int ni = 0; ni < 4; ni++) bfr[ni] = *(const short8*)&Bz[(wc*64 + ni*16 + l16)*32 + kq*8];
    f32x4 acc[4][4];
#pragma unroll
    for (int i = 0; i < 4; i++)
#pragma unroll
      for (int j = 0; j < 4; j++) acc[i][j] = (f32x4)0.0f;
#pragma unroll
    for (int mi = 0; mi < 4; mi++)
#pragma unroll
      for (int ni = 0; ni < 4; ni++)
        acc[mi][ni] = __builtin_amdgcn_mfma_f32_16x16x32_bf16(af[mi], bfr[ni], acc[mi][ni], 0, 0, 0);

    const float* tm = mp.tm[z];
    float tmv[4];
#pragma unroll
    for (int ni = 0; ni < 4; ni++) tmv[ni] = tm[col0 + wc*64 + ni*16 + l16];
    u16* C = mp.out[z];
#pragma unroll
    for (int mi = 0; mi < 4; mi++){
#pragma unroll
      for (int qq = 0; qq < 4; qq++){
        const long r = row0 + wr*64 + mi*16 + kq*4 + qq;
        u16* crow = C + r * 1024 + col0 + wc*64 + l16;
#pragma unroll
        for (int ni = 0; ni < 4; ni++){
          const u32 pk = pxx[mi*16 + qq*4 + ni];
          const float xc = b2f(LOH(pk));
          const float xx = b2f(HIH(pk));
          crow[ni * 16] = f2b(xc + xx * (tmv[ni] + acc[mi][ni][qq]));
        }
      }
    }
  }
}

// ---------------------------------------------------------------------------
// Fused prep + mkxm (one launch).  y<9: weight prep slices.
// y in [9,17): XM = bf16(x + (xp-x)*tmx); PXX = bf16(x) | bf16(xp-x)<<16.
// ---------------------------------------------------------------------------
struct PrepMkP { const float* s[5]; u16* d[5];
                 const float* mw1; const float* mw2; const float* tdw1; const float* tdw2;
                 u16* w1t; u16* w2t; u16* tw1t; u16* tw2t;
                 const float* X; const float* tmx; u16* XM; u32* PXX; };
__global__ __launch_bounds__(256) void prepmk_k(PrepMkP pp)
{
  const int y = blockIdx.y;
  if (y < 9){
    const long idx = (long)blockIdx.x * 256 + threadIdx.x;
    if (y < 5){
      const float4 v = ((const float4*)pp.s[y])[idx];
      ushort4 o; o.x = f2b(v.x); o.y = f2b(v.y); o.z = f2b(v.z); o.w = f2b(v.w);
      ((ushort4*)pp.d[y])[idx] = o;
    } else if (y == 5){
      const int k = (int)(idx & 1023);       // idx = n*1024 + k
      const int n = (int)(idx >> 10);
      pp.w1t[idx] = (n < 160) ? f2b(pp.mw1[(long)k * 160 + n]) : (u16)0;
    } else if (y == 6){
      if (idx >= 163840) return;
      const int k = (int)(idx & 31);
      const int col = (int)(idx >> 5) & 1023;
      const int f = (int)(idx >> 15);
      pp.w2t[idx] = f2b(pp.mw2[f * 32768 + k * 1024 + col]);
    } else if (y == 7){
      if (idx >= 131072) return;
      const int k = (int)(idx & 1023);
      const int n = (int)(idx >> 10);
      pp.tw1t[idx] = (n < 64) ? f2b(pp.tdw1[(long)k * 64 + n]) : (u16)0;
    } else {
      if (idx >= 65536) return;
      const int k = (int)(idx & 63);
      const int n = (int)(idx >> 6);
      pp.tw2t[idx] = f2b(pp.tdw2[(long)k * 1024 + n]);
    }
    return;
  }
  // mkxm part: 8 y-slices x 1024 x-blocks = 8192 logical blocks
  const long idx = (((long)(y - 9) * 1024 + blockIdx.x) * 256 + threadIdx.x);
  const long m = idx >> 8;
  const int c4 = (int)(idx & 255) * 4;
  const float4 x = *(const float4*)(pp.X + m * 1024 + c4);
  float4 p = make_float4(0.f, 0.f, 0.f, 0.f);
  if ((m & 2047) != 0) p = *(const float4*)(pp.X + (m - 1) * 1024 + c4);
  const float4 t = *(const float4*)(pp.tmx + c4);
  ushort4 o;
  o.x = f2b(x.x + (p.x - x.x) * t.x);
  o.y = f2b(x.y + (p.y - x.y) * t.y);
  o.z = f2b(x.z + (p.z - x.z) * t.z);
  o.w = f2b(x.w + (p.w - x.w) * t.w);
  *(ushort4*)(pp.XM + m * 1024 + c4) = o;
  uint4 px;
  px.x = (u32)f2b(x.x) | ((u32)f2b(p.x - x.x) << 16);
  px.y = (u32)f2b(x.y) | ((u32)f2b(p.y - x.y) << 16);
  px.z = (u32)f2b(x.z) | ((u32)f2b(p.z - x.z) << 16);
  px.w = (u32)f2b(x.w) | ((u32)f2b(p.w - x.w) << 16);
  *(uint4*)(pp.PXX + m * 1024 + c4) = px;
}

// ---------------------------------------------------------------------------
// WKV6 stage 1 (MFMA) + fused DEC.  Block per (b,h,chunk).
//  DEC = exp(-exp(Hb@TW2T^T + td)) computed in-kernel (K=64, one 64x64 tile),
//  then: M = r̃·k̃ᵀ (masked), Y = M·V + diag·v (bf16), A = k̃ᵀ·V (bf16 out),
//  r̃ -> Rg, Pg.  P0c prefix-decay parallelized 4x via segmented scan.
//  Fast exp2-based transcendentals (R23).
// ---------------------------------------------------------------------------
__global__ __launch_bounds__(256) void wkv_s1(
    u16* __restrict__ Rg, const u16* __restrict__ Kg, const u16* __restrict__ Vg,
    const u16* __restrict__ Hbg, const u16* __restrict__ TW2Tg,
    const float* __restrict__ TDg, const float* __restrict__ Ug,
    u16* __restrict__ Yg, u16* __restrict__ Ag, float* __restrict__ Pg)
{
  __shared__ u16 RT_[64 * 72];     // Hb tile -> r -> r̃  [i][k]
  __shared__ u16 KT_[64 * 72];     // TW2T tile -> k -> k̃  [s][k]
  __shared__ u16 KTT_[64 * 72];    // k̃ᵀ [k][s]
  __shared__ u16 V_[64 * 72];      // V [s][j]
  __shared__ u16 VT_[64 * 72];     // Vᵀ [j][s]
  __shared__ char UD_[64 * 68 * 4];// DEC f32 [i][68], then M u16 [i][72]
  __shared__ float us_[64];
  __shared__ float td_[64];
  __shared__ float dg4_[256];
  __shared__ float dg_[64];
  __shared__ float segp_[256];     // [seg][k] local decay products
  float* D_ = (float*)UD_;
  u16*  M_  = (u16*)UD_;

  const int tid = threadIdx.x;
  const int bh = blockIdx.x >> 5, ch = blockIdx.x & 31;
  const int b = bh >> 4, h = bh & 15, cb = h * 64;
  const long rowb = (long)b * 2048 + ch * 64;

  if (tid < 64){ us_[tid] = Ug[cb + tid]; td_[tid] = TDg[cb + tid]; }

  const int iS = tid >> 2, sg = tid & 3;
  // ---- P(-1): stage Hb[rowb..+64][0..64) -> RT_, TW2T[cb..+64][64] -> KT_
  {
    const uint4* hsrc = (const uint4*)(Hbg + (rowb + iS) * 128 + sg * 16);
    uint4* hdst = (uint4*)&RT_[iS * 72 + sg * 16];
    hdst[0] = hsrc[0]; hdst[1] = hsrc[1];
    const uint4* wsrc = (const uint4*)(TW2Tg + (cb + iS) * 64 + sg * 16);
    uint4* wdst = (uint4*)&KT_[iS * 72 + sg * 16];
    wdst[0] = wsrc[0]; wdst[1] = wsrc[1];
  }
  __syncthreads();
  // ---- DEC MFMA: acc = Hb_tile @ TW2T_tile^T (K=64); D_ = exp(-exp(acc+td))
  {
    const int wave = tid >> 6, lane = tid & 63;
    const int wr = wave >> 1, wc = wave & 1;
    const int l16 = lane & 15, kq = lane >> 4;
    f32x4 dacc[2][2];
#pragma unroll
    for (int a = 0; a < 2; a++)
#pragma unroll
      for (int c = 0; c < 2; c++) dacc[a][c] = (f32x4)0.0f;
#pragma unroll
    for (int ks = 0; ks < 2; ks++){
      short8 af[2], bf[2];
#pragma unroll
      for (int mi = 0; mi < 2; mi++) af[mi] = *(const short8*)&RT_[(wr*32 + mi*16 + l16)*72 + ks*32 + kq*8];
#pragma unroll
      for (int ni = 0; ni < 2; ni++) bf[ni] = *(const short8*)&KT_[(wc*32 + ni*16 + l16)*72 + ks*32 + kq*8];
#pragma unroll
      for (int mi = 0; mi < 2; mi++)
#pragma unroll
        for (int ni = 0; ni < 2; ni++)
          dacc[mi][ni] = __builtin_amdgcn_mfma_f32_16x16x32_bf16(af[mi], bf[ni], dacc[mi][ni], 0, 0, 0);
    }
    __syncthreads();   // all RT_/KT_ reads complete before r/k/v staging overwrites
#pragma unroll
    for (int mi = 0; mi < 2; mi++)
#pragma unroll
      for (int ni = 0; ni < 2; ni++)
#pragma unroll
        for (int qq = 0; qq < 4; qq++){
          const int ii = wr*32 + mi*16 + kq*4 + qq;
          const int jj = wc*32 + ni*16 + l16;
          D_[ii * 68 + jj] = fexp(-fexp(dacc[mi][ni][qq] + td_[jj]));
        }
  }
  // ---- P0: stage r,k,v(,vT)
  {
    const long go = (rowb + iS) * 1024 + cb + sg * 16;
    uint4 a0 = *(const uint4*)(Rg + go);
    uint4 a1 = *(const uint4*)(Rg + go + 8);
    u32* rd = (u32*)&RT_[iS * 72 + sg * 16];
    rd[0]=a0.x; rd[1]=a0.y; rd[2]=a0.z; rd[3]=a0.w;
    rd[4]=a1.x; rd[5]=a1.y; rd[6]=a1.z; rd[7]=a1.w;
    a0 = *(const uint4*)(Kg + go); a1 = *(const uint4*)(Kg + go + 8);
    u32* kd = (u32*)&KT_[iS * 72 + sg * 16];
    kd[0]=a0.x; kd[1]=a0.y; kd[2]=a0.z; kd[3]=a0.w;
    kd[4]=a1.x; kd[5]=a1.y; kd[6]=a1.z; kd[7]=a1.w;
    a0 = *(const uint4*)(Vg + go); a1 = *(const uint4*)(Vg + go + 8);
    u32* vd = (u32*)&V_[iS * 72 + sg * 16];
    vd[0]=a0.x; vd[1]=a0.y; vd[2]=a0.z; vd[3]=a0.w;
    vd[4]=a1.x; vd[5]=a1.y; vd[6]=a1.z; vd[7]=a1.w;
    const u32 vw[8] = {a0.x,a0.y,a0.z,a0.w,a1.x,a1.y,a1.z,a1.w};
#pragma unroll
    for (int e = 0; e < 8; e++){
      VT_[(sg*16 + 2*e    ) * 72 + iS] = LOH(vw[e]);
      VT_[(sg*16 + 2*e + 1) * 72 + iS] = HIH(vw[e]);
    }
  }
  __syncthreads();
  // ---- P0b: diag partials with RAW r,k
  {
    const int i = tid & 63, q = tid >> 6;
    const u32* rr = (const u32*)&RT_[i * 72 + q * 16];
    const u32* kr = (const u32*)&KT_[i * 72 + q * 16];
    const float* up = &us_[q * 16];
    float ds = 0.0f;
#pragma unroll
    for (int e = 0; e < 8; e++){
      ds += b2f(LOH(rr[e])) * up[2*e]   * b2f(LOH(kr[e]));
      ds += b2f(HIH(rr[e])) * up[2*e+1] * b2f(HIH(kr[e]));
    }
    dg4_[i * 4 + q] = ds;
  }
  __syncthreads();
  // ---- P0c (4x parallel segmented scan): prefix decay; RT->r̃, KT->k̃ (+KTT)
  {
    const int k = tid & 63, seg = tid >> 6;
    if (seg == 0) dg_[k] = dg4_[k*4] + dg4_[k*4+1] + dg4_[k*4+2] + dg4_[k*4+3];
    const int i0 = seg * 16;
    float lp = 1.0f;
#pragma unroll
    for (int i = 0; i < 16; i++) lp *= D_[(i0 + i) * 68 + k];
    segp_[seg * 64 + k] = lp;
    __syncthreads();
    float pz = 1.0f;
    for (int s = 0; s < seg; s++) pz *= segp_[s * 64 + k];
#pragma unroll
    for (int i = 0; i < 16; i++){
      const int ii = i0 + i;
      const float d = D_[ii * 68 + k];
      const int ro = ii * 72 + k;
      RT_[ro] = f2b(b2f(RT_[ro]) * pz);
      pz *= d;
      const u16 kb = f2b(b2f(KT_[ro]) * __builtin_amdgcn_rcpf(pz));
      KT_[ro] = kb;
      KTT_[k * 72 + ii] = kb;
    }
    if (seg == 3) Pg[((long)bh * 32 + ch) * 64 + k] = pz;
  }
  __syncthreads();
  // ---- writeback r̃ to Rg
  {
    const u32* rr = (const u32*)&RT_[iS * 72 + sg * 16];
    u32* out = (u32*)(Rg + (rowb + iS) * 1024 + cb + sg * 16);
#pragma unroll
    for (int e = 0; e < 8; e++) out[e] = rr[e];
  }
  const int wave = tid >> 6, lane = tid & 63;
  const int wr = wave >> 1, wc = wave & 1;
  const int l16 = lane & 15, kq = lane >> 4;
  // ---- P2: M = r̃·k̃ᵀ, mask s<i, store bf16 to M_
  {
    f32x4 acc[2][2];
#pragma unroll
    for (int a = 0; a < 2; a++)
#pragma unroll
      for (int c = 0; c < 2; c++) acc[a][c] = (f32x4)0.0f;
#pragma unroll
    for (int ks = 0; ks < 2; ks++){
      short8 af[2], bf[2];
#pragma unroll
      for (int mi = 0; mi < 2; mi++) af[mi] = *(const short8*)&RT_[(wr*32 + mi*16 + l16)*72 + ks*32 + kq*8];
#pragma unroll
      for (int ni = 0; ni < 2; ni++) bf[ni] = *(const short8*)&KT_[(wc*32 + ni*16 + l16)*72 + ks*32 + kq*8];
#pragma unroll
      for (int mi = 0; mi < 2; mi++)
#pragma unroll
        for (int ni = 0; ni < 2; ni++)
          acc[mi][ni] = __builtin_amdgcn_mfma_f32_16x16x32_bf16(af[mi], bf[ni], acc[mi][ni], 0, 0, 0);
    }
    __syncthreads();    // D_ dead; M_ union becomes valid
#pragma unroll
    for (int mi = 0; mi < 2; mi++)
#pragma unroll
      for (int ni = 0; ni < 2; ni++)
#pragma unroll
        for (int qq = 0; qq < 4; qq++){
          const int ii = wr*32 + mi*16 + kq*4 + qq;
          const int ss = wc*32 + ni*16 + l16;
          M_[ii * 72 + ss] = f2b(ss < ii ? acc[mi][ni][qq] : 0.0f);
        }
  }
  __syncthreads();
  // ---- P3+P4: Y = M·V + diag·v ; A = k̃ᵀ·V (bf16 out)
  {
    f32x4 accY[2][2], accA[2][2];
#pragma unroll
    for (int a = 0; a < 2; a++)
#pragma unroll
      for (int c = 0; c < 2; c++){ accY[a][c] = (f32x4)0.0f; accA[a][c] = (f32x4)0.0f; }
#pragma unroll
    for (int ks = 0; ks < 2; ks++){
      short8 am[2], ak[2], bv[2];
#pragma unroll
      for (int mi = 0; mi < 2; mi++){
        am[mi] = *(const short8*)&M_[(wr*32 + mi*16 + l16)*72 + ks*32 + kq*8];
        ak[mi] = *(const short8*)&KTT_[(wr*32 + mi*16 + l16)*72 + ks*32 + kq*8];
      }
#pragma unroll
      for (int ni = 0; ni < 2; ni++) bv[ni] = *(const short8*)&VT_[(wc*32 + ni*16 + l16)*72 + ks*32 + kq*8];
#pragma unroll
      for (int mi = 0; mi < 2; mi++)
#pragma unroll
        for (int ni = 0; ni < 2; ni++){
          accY[mi][ni] = __builtin_amdgcn_mfma_f32_16x16x32_bf16(am[mi], bv[ni], accY[mi][ni], 0, 0, 0);
          accA[mi][ni] = __builtin_amdgcn_mfma_f32_16x16x32_bf16(ak[mi], bv[ni], accA[mi][ni], 0, 0, 0);
        }
    }
    u16* abase = Ag + ((long)bh * 32 + ch) * 4096;
#pragma unroll
    for (int mi = 0; mi < 2; mi++)
#pragma unroll
      for (int qq = 0; qq < 4; qq++){
        const int ii = wr*32 + mi*16 + kq*4 + qq;
        u16* yrow = Yg + (rowb + ii) * 1024 + cb;
        u16* arow = abase + ii * 64;
#pragma unroll
        for (int ni = 0; ni < 2; ni++){
          const int jj = wc*32 + ni*16 + l16;
          const float yv = accY[mi][ni][qq] + dg_[ii] * b2f(V_[ii * 72 + jj]);
          yrow[jj] = f2b(yv);
          arow[jj] = f2b(accA[mi][ni][qq]);
        }
      }
  }
}

// ---------------------------------------------------------------------------
// WKV6 stage 2 — inter-chunk recurrence S_{c+1} = ps_c*(S_c + A_c).
// A and S in bf16 (state kept f32 in regs).  8-deep load prefetch.
// ---------------------------------------------------------------------------
__global__ __launch_bounds__(256) void wkv_s2(
    const u16* __restrict__ Ag, const float* __restrict__ Pg, u16* __restrict__ Sg)
{
  const int tid = threadIdx.x;
  const int bh = blockIdx.x >> 2, kq = blockIdx.x & 3;
  const int kk = tid >> 4, jo = tid & 15;
  const int krow = kq * 16 + kk;
  const long base = (long)bh * 32;
  float4 S = make_float4(0.f, 0.f, 0.f, 0.f);
  for (int g = 0; g < 4; g++){
    uint2 a[8]; float ps[8];
#pragma unroll
    for (int j = 0; j < 8; j++){
      const long c = base + g * 8 + j;
      a[j]  = *(const uint2*)(Ag + c * 4096 + krow * 64 + jo * 4);
      ps[j] = Pg[c * 64 + krow];
    }
#pragma unroll
    for (int j = 0; j < 8; j++){
      const long mo = (base + g * 8 + j) * 4096 + krow * 64 + jo * 4;
      uint2 so;
      so.x = (u32)f2b(S.x) | ((u32)f2b(S.y) << 16);
      so.y = (u32)f2b(S.z) | ((u32)f2b(S.w) << 16);
      *(uint2*)(Sg + mo) = so;
      const float a0 = b2f(LOH(a[j].x)), a1 = b2f(HIH(a[j].x));
      const float a2 = b2f(LOH(a[j].y)), a3 = b2f(HIH(a[j].y));
      S.x = ps[j] * (S.x + a0); S.y = ps[j] * (S.y + a1);
      S.z = ps[j] * (S.z + a2); S.w = ps[j] * (S.w + a3);
    }
  }
}

// ---------------------------------------------------------------------------
// WKV6 stage 3 + GroupNorm fused:  y = Y + r̃·S_chunkstart (ch>0), then
// per-head GN over the 64 channels this block owns, * g, write Z (bf16).
// R24: cross-term r̃·S (64x64x64 matmul) moved from VALU loop to MFMA —
// stage r̃ [i][k] and Sᵀ [j][k] bf16 in LDS, 8 MFMAs, product -> yt f32 LDS.
// ---------------------------------------------------------------------------
__global__ __launch_bounds__(256) void wkv_s3g(
    const u16* __restrict__ Rtg, const u16* __restrict__ Sg,
    const u16* __restrict__ Yg, const u16* __restrict__ G,
    const float* __restrict__ lng, const float* __restrict__ lnb,
    u16* __restrict__ Z)
{
  __shared__ u16 RTs[64 * 72];      // r̃ [i][k]
  __shared__ u16 STs[64 * 72];      // Sᵀ [j][k]
  __shared__ float yt[64 * 68];     // r̃·S product f32 [i][j]
  __shared__ float red1[256], red2[256];
  const int tid = threadIdx.x;
  const int bh = blockIdx.x >> 5, ch = blockIdx.x & 31;
  const int b = bh >> 4, h = bh & 15, cb = h * 64;
  const long rowb = (long)b * 2048 + ch * 64;
  const bool CROSS = (ch != 0);

  if (CROSS){
    const int iS = tid >> 2, sg4 = tid & 3;
    // r̃ rows [i][k]
    const uint4* src = (const uint4*)(Rtg + (rowb + iS) * 1024 + cb + sg4 * 16);
    uint4* dst = (uint4*)&RTs[iS * 72 + sg4 * 16];
    dst[0] = src[0]; dst[1] = src[1];
    // Sᵀ scatter: S [k][j] bf16 -> STs[j][k]
    const u16* sb = Sg + ((long)bh * 32 + ch) * 4096 + iS * 64 + sg4 * 16;
    const uint4 s0 = *(const uint4*)sb;
    const uint4 s1 = *(const uint4*)(sb + 8);
    const u32 w[8] = {s0.x, s0.y, s0.z, s0.w, s1.x, s1.y, s1.z, s1.w};
#pragma unroll
    for (int e = 0; e < 8; e++){
      STs[(sg4*16 + 2*e    ) * 72 + iS] = LOH(w[e]);
      STs[(sg4*16 + 2*e + 1) * 72 + iS] = HIH(w[e]);
    }
  }
  __syncthreads();
  if (CROSS){
    const int wave = tid >> 6, lane = tid & 63;
    const int wr = wave >> 1, wc = wave & 1;
    const int l16 = lane & 15, kq = lane >> 4;
    f32x4 acc[2][2];
#pragma unroll
    for (int a = 0; a < 2; a++)
#pragma unroll
      for (int c = 0; c < 2; c++) acc[a][c] = (f32x4)0.0f;
#pragma unroll
    for (int ks = 0; ks < 2; ks++){
      short8 af[2], bf[2];
#pragma unroll
      for (int mi = 0; mi < 2; mi++) af[mi] = *(const short8*)&RTs[(wr*32 + mi*16 + l16)*72 + ks*32 + kq*8];
#pragma unroll
      for (int ni = 0; ni < 2; ni++) bf[ni] = *(const short8*)&STs[(wc*32 + ni*16 + l16)*72 + ks*32 + kq*8];
#pragma unroll
      for (int mi = 0; mi < 2; mi++)
#pragma unroll
        for (int ni = 0; ni < 2; ni++)
          acc[mi][ni] = __builtin_amdgcn_mfma_f32_16x16x32_bf16(af[mi], bf[ni], acc[mi][ni], 0, 0, 0);
    }
#pragma unroll
    for (int mi = 0; mi < 2; mi++)
#pragma unroll
      for (int ni = 0; ni < 2; ni++)
#pragma unroll
        for (int qq = 0; qq < 4; qq++){
          const int ii = wr*32 + mi*16 + kq*4 + qq;
          const int jj = wc*32 + ni*16 + l16;
          yt[ii * 68 + jj] = acc[mi][ni][qq];
        }
  }
  __syncthreads();

  const int i_ = tid & 63, q = tid >> 6, jb = q * 16;
  float y[16];
  {
    const u32* yp = (const u32*)(Yg + (rowb + i_) * 1024 + cb + jb);
#pragma unroll
    for (int j2 = 0; j2 < 8; j2++){
      const u32 u = yp[j2];
      y[2*j2] = b2f(LOH(u)); y[2*j2+1] = b2f(HIH(u));
    }
  }
  if (CROSS){
    const float* yr = &yt[i_ * 68 + jb];
#pragma unroll
    for (int j = 0; j < 16; j++) y[j] += yr[j];
  }
  // group-norm reduce across the 4 q-quarters of each row
  float s = 0.0f, sq = 0.0f;
#pragma unroll
  for (int j = 0; j < 16; j++){ s += y[j]; sq += y[j]*y[j]; }
  red1[q * 64 + i_] = s;
  red2[q * 64 + i_] = sq;
  __syncthreads();
  const float St = red1[i_] + red1[64 + i_] + red1[128 + i_] + red1[192 + i_];
  const float Qt = red2[i_] + red2[64 + i_] + red2[128 + i_] + red2[192 + i_];
  const float mean = St * 0.015625f;
  const float var = Qt * 0.015625f - mean * mean;
  const float rstd = rsqrtf(var + 6.4e-4f);   // eps = 1e-5 * 64
  const u32* gp = (const u32*)(G + (rowb + i_) * 1024 + cb + jb);
  const float4* lgp = (const float4*)(lng + cb + jb);
  const float4* lbp = (const float4*)(lnb + cb + jb);
  u32* zo = (u32*)(Z + (rowb + i_) * 1024 + cb + jb);
#pragma unroll
  for (int j4 = 0; j4 < 4; j4++){
    const float4 lg = lgp[j4];
    const float4 lb = lbp[j4];
    const u32 g01 = gp[2*j4], g23 = gp[2*j4+1];
    const float z0 = ((y[4*j4+0]-mean)*rstd*lg.x + lb.x) * b2f(LOH(g01));
    const float z1 = ((y[4*j4+1]-mean)*rstd*lg.y + lb.y) * b2f(HIH(g01));
    const float z2 = ((y[4*j4+2]-mean)*rstd*lg.z + lb.z) * b2f(LOH(g23));
    const float z3 = ((y[4*j4+3]-mean)*rstd*lg.w + lb.w) * b2f(HIH(g23));
    zo[2*j4]   = (u32)f2b(z0) | ((u32)f2b(z1) << 16);
    zo[2*j4+1] = (u32)f2b(z2) | ((u32)f2b(z3) << 16);
  }
}

// ---------------------------------------------------------------------------
extern "C" void kernel_launch(void* const* d_in, const int* in_sizes, int n_in,
                              void* d_out, int out_size, void* d_ws, size_t ws_size,
                              hipStream_t stream)
{
  (void)in_sizes; (void)n_in; (void)out_size; (void)ws_size;
  const float* X    = (const float*)d_in[0];
  const float* TMX  = (const float*)d_in[1];
  const float* TMW  = (const float*)d_in[2];
  const float* TMK  = (const float*)d_in[3];
  const float* TMV  = (const float*)d_in[4];
  const float* TMR  = (const float*)d_in[5];
  const float* TMG  = (const float*)d_in[6];
  const float* MW1  = (const float*)d_in[7];
  const float* MW2  = (const float*)d_in[8];
  const float* TD   = (const float*)d_in[9];
  const float* TDW1 = (const float*)d_in[10];
  const float* TDW2 = (const float*)d_in[11];
  const float* U    = (const float*)d_in[12];
  const float* WR   = (const float*)d_in[13];
  const float* WK   = (const float*)d_in[14];
  const float* WV   = (const float*)d_in[15];
  const float* WG   = (const float*)d_in[16];
  const float* WO   = (const float*)d_in[17];
  const float* LNG  = (const float*)d_in[18];
  const float* LNB  = (const float*)d_in[19];

  char* ws = (char*)d_ws;
  const size_t SLOT = 16777216ULL;     // B*T*C bf16 bytes
  u16* S1 = (u16*)(ws + 0 * SLOT);     // XM  -> Rb (-> rt~)
  u16* S2 = (u16*)(ws + 1 * SLOT);     // XW  -> Y (bf16)
  u16* S3 = (u16*)(ws + 2 * SLOT);     // XK
  u16* S4 = (u16*)(ws + 3 * SLOT);     // XV  -> Z
  u16* S5 = (u16*)(ws + 4 * SLOT);     // XR
  u16* S6 = (u16*)(ws + 5 * SLOT);     // XG
  u16* S7 = (u16*)(ws + 6 * SLOT);     // PXX lo -> Kb -> Sg (bf16)
  u16* S8 = (u16*)(ws + 7 * SLOT);     // PXX hi -> Vb
  u16* S9 = (u16*)(ws + 8 * SLOT);     // Gb
  char* p = ws + 9 * SLOT;
  auto alloc = [&](size_t bytes) -> void* {
    void* q = p; p += (bytes + 255) & ~(size_t)255; return q;
  };
  u16* MIXB = (u16*)alloc(8192ULL * 256 * 2);
  u16* Hb   = (u16*)alloc(8192ULL * 128 * 2);
  u16* W1T  = (u16*)alloc(256ULL * 1024 * 2);
  u16* W2T  = (u16*)alloc(5ULL * 1024 * 32 * 2);
  u16* TW1T = (u16*)alloc(128ULL * 1024 * 2);
  u16* TW2T = (u16*)alloc(1024ULL * 64 * 2);
  u16* WRb  = (u16*)alloc(1048576ULL * 2);
  u16* WKb  = (u16*)alloc(1048576ULL * 2);
  u16* WVb  = (u16*)alloc(1048576ULL * 2);
  u16* WGb  = (u16*)alloc(1048576ULL * 2);
  u16* WOb  = (u16*)alloc(1048576ULL * 2);
  u16* Ab   = (u16*)alloc(16777216ULL);     // [bh][c][64][64] bf16
  float* Pg = (float*)alloc(524288ULL);     // [bh][c][64] f32

  u16*   XM = S1; u16* XW = S2; u16* XK = S3; u16* XV = S4; u16* XR = S5; u16* XG = S6;
  u32*   PXX = (u32*)S7;      // spans S7+S8 (32 MB)
  u16*   Rb = S1; u16* Kb = S7; u16* Vb = S8; u16* Gb = S9;
  u16*   Y   = S2;            // bf16 (xw dead after combined gemm)
  u16*   Sg  = S7;            // bf16, 16.77 MB (kb dead after s1)
  u16*   Z   = S4;            // xv dead

  // allow 80KB dynamic LDS for gemm_mix5 (idempotent, cheap host call)
  hipFuncSetAttribute(reinterpret_cast<const void*>(gemm_mix5),
                      hipFuncAttributeMaxDynamicSharedMemorySize, 81920);

  // fused weight prep + XM/PXX — one launch (independent work items)
  PrepMkP pp;
  pp.s[0]=WR; pp.s[1]=WK; pp.s[2]=WV; pp.s[3]=WG; pp.s[4]=WO;
  pp.d[0]=WRb; pp.d[1]=WKb; pp.d[2]=WVb; pp.d[3]=WGb; pp.d[4]=WOb;
  pp.mw1 = MW1; pp.mw2 = MW2; pp.tdw1 = TDW1; pp.tdw2 = TDW2;
  pp.w1t = W1T; pp.w2t = W2T; pp.tw1t = TW1T; pp.tw2t = TW2T;
  pp.X = X; pp.tmx = TMX; pp.XM = XM; pp.PXX = PXX;
  prepmk_k<<<dim3(1024, 17), 256, 0, stream>>>(pp);

  // mix160 = tanh(XM @ maa_w1)  [8192,256(pad)] — full-GPU 64x128 tiles
  gemm_tanh64<<<dim3(128, 2), 256, 0, stream>>>(XM, W1T, MIXB);

  // x{w,k,v,r,g} = x + xx*(tm + mix_f @ maa_w2_f) — one launch, single barrier
  Mix5P mp;
  mp.pxx = PXX;
  mp.out[0]=XW; mp.out[1]=XK; mp.out[2]=XV; mp.out[3]=XR; mp.out[4]=XG;
  mp.tm[0]=TMW; mp.tm[1]=TMK; mp.tm[2]=TMV; mp.tm[3]=TMR; mp.tm[4]=TMG;
  gemm_mix5<<<dim3(64, 8), 256, 81920, stream>>>(MIXB, W2T, mp);

  // r, k, v, g (z=0..3) + Hb = tanh(xw @ td_w1) (z=4, N=128) — ONE dispatch
  G4P gp;
  gp.A[0]=XR; gp.A[1]=XK; gp.A[2]=XV; gp.A[3]=XG; gp.A[4]=XW;
  gp.B[0]=WRb; gp.B[1]=WKb; gp.B[2]=WVb; gp.B[3]=WGb; gp.B[4]=TW1T;
  gp.C[0]=Rb; gp.C[1]=Kb; gp.C[2]=Vb; gp.C[3]=Gb; gp.C[4]=Hb;
  gemm128_k<0><<<dim3(64, 8, 5), 256, 0, stream>>>(gp, nullptr);

  // WKV6 chunk-parallel scan (Y bf16); s1 fuses DEC, s3 fuses GroupNorm -> Z
  wkv_s1<<<2048, 256, 0, stream>>>(Rb, Kb, Vb, Hb, TW2T, TD, U, Y, Ab, Pg);
  wkv_s2<<<256, 256, 0, stream>>>(Ab, Pg, Sg);
  wkv_s3g<<<2048, 256, 0, stream>>>(Rb, Sg, Y, Gb, LNG, LNB, Z);

  // out = z @ Wo^T   (f32 out)
  G4P go;
  go.A[0]=Z; go.B[0]=WOb; go.C[0]=nullptr;
  gemm128_k<1><<<dim3(64, 8, 1), 256, 0, stream>>>(go, (float*)d_out);
}